// Round 14
// baseline (232.186 us; speedup 1.0000x reference)
//
#include <hip/hip_runtime.h>

// Bilinear resampling: feature_map [C,H,W] fp32, target_uv [N,2] fp32, downscale (int scalar)
// out [C,N] fp32.
//
// R14: R12 aux (k0_zero + 1024t scan, measured-best) + R13 k4 with the staging
// batch pinned by REGISTER LIVENESS (asm "+v" on all stg regs: allocator must
// keep 4x float4 in flight; sched_barrier alone left VGPR=20 i.e. serialized).
// Gather uses float2 LDS reads (8x ds_read_b64). Paired-cg mid, 8B records.
constexpr int C = 128, H = 376, W = 1248;
constexpr int HW = H * W;

constexpr int BIN  = 20;
constexpr int BU   = (W + BIN - 1) / BIN;   // 63
constexpr int BV   = (H + BIN - 1) / BIN;   // 19
constexpr int NBINS = BU * BV;              // 1197
constexpr int CPG  = 8;                     // channels per k4 block
constexpr int NCG  = C / CPG;               // 16
constexpr int ROWS = BIN + 1;               // 21 region rows
constexpr int CHROW = 6;                    // float4 chunks per row (24 floats >= 21)
constexpr int RWF  = CHROW * 4;             // 24 floats row stride
constexpr int CH_CHUNKS = ROWS * CHROW + 1; // 127 chunks (126 used + 1 pad)
constexpr int CH_F = CH_CHUNKS * 4;         // 508 floats: quad stride 2032 % 32 = 16 -> conflict-free
constexpr int BLK_CHUNKS = CPG * CH_CHUNKS; // 1016 chunks -> 16,256 B LDS
constexpr int STG = (BLK_CHUNKS + 255) / 256; // 4 staging registers (float4)

typedef float vfloat4 __attribute__((ext_vector_type(4)));
typedef float vfloat2 __attribute__((ext_vector_type(2)));

__global__ __launch_bounds__(512) void k0_zero(int* hist, int* cursor) {
    for (int i = threadIdx.x; i < NBINS; i += 512) { hist[i] = 0; cursor[i] = 0; }
}

__global__ __launch_bounds__(256) void k1_count(const float* __restrict__ uv,
                                                const int* __restrict__ dsp,
                                                int* __restrict__ hist, int N) {
    __shared__ int lh[NBINS];
    for (int i = threadIdx.x; i < NBINS; i += 256) lh[i] = 0;
    __syncthreads();
    int n = blockIdx.x * 256 + threadIdx.x;
    if (n < N) {
        float dsf = (float)dsp[0];
        float2 p = ((const float2*)uv)[n];
        int ul = (int)(p.x / dsf);
        int vl = (int)(p.y / dsf);
        atomicAdd(&lh[(vl / BIN) * BU + (ul / BIN)], 1);
    }
    __syncthreads();
    for (int i = threadIdx.x; i < NBINS; i += 256)
        if (lh[i]) atomicAdd(hist + i, lh[i]);
}

// 2-chunk carry scan (NBINS=1197 > 1024) — R12's measured-good version.
__global__ __launch_bounds__(1024) void k2_scan(const int* __restrict__ hist,
                                                int* __restrict__ starts,
                                                int* __restrict__ cursor) {
    __shared__ int sh[1024];
    __shared__ int carry_s;
    int t = threadIdx.x;
    if (t == 0) { carry_s = 0; starts[0] = 0; }
    __syncthreads();
    constexpr int NCHUNK = (NBINS + 1023) / 1024;
    for (int chunk = 0; chunk < NCHUNK; ++chunk) {
        int i = chunk * 1024 + t;
        int val = (i < NBINS) ? hist[i] : 0;
        sh[t] = val;
        __syncthreads();
        for (int off = 1; off < 1024; off <<= 1) {
            int v = (t >= off) ? sh[t - off] : 0;
            __syncthreads();
            sh[t] += v;
            __syncthreads();
        }
        int cbase = carry_s;
        int incl  = sh[t] + cbase;
        if (i < NBINS) {
            starts[i + 1] = incl;
            cursor[i] = incl - val;      // exclusive
        }
        __syncthreads();
        if (t == 1023) carry_s = cbase + sh[1023];
        __syncthreads();
    }
}

__global__ __launch_bounds__(256) void k3_scatter(const float* __restrict__ uv,
                                                  const int* __restrict__ dsp,
                                                  int* __restrict__ cursor,
                                                  float2* __restrict__ sortedUV,
                                                  int* __restrict__ inv, int N) {
    int n = blockIdx.x * 256 + threadIdx.x;
    if (n >= N) return;
    float dsf = (float)dsp[0];
    float2 p = ((const float2*)uv)[n];
    int ul = (int)(p.x / dsf);
    int vl = (int)(p.y / dsf);
    int bin = (vl / BIN) * BU + (ul / BIN);
    int pos = atomicAdd(cursor + bin, 1);
    sortedUV[pos] = p;            // 8B record; k4 re-derives everything
    inv[n] = pos;                 // coalesced: dest-side permutation index
}

// k4: (bin, cg) blocks. Batched REGISTER staging, batch pinned by asm liveness.
// Gather: 2 lanes/point, float2 LDS reads, paired-cg mid[cg>>1][p][16].
__global__ __launch_bounds__(256) void k4_resample(const float* __restrict__ fmap,
                                                   const float2* __restrict__ sortedUV,
                                                   const int* __restrict__ starts,
                                                   const int* __restrict__ dsp,
                                                   float* __restrict__ mid, int N) {
    __shared__ float lds[BLK_CHUNKS * 4];   // 16,256 B -> 8 blocks/CU

    int bin = blockIdx.x >> 4;      // / NCG
    int cg  = blockIdx.x & 15;      // % NCG
    int bu  = bin % BU;
    int bv  = bin / BU;
    int u0  = bu * BIN;
    int v0  = bv * BIN;
    int cb  = cg * CPG;
    int tid = threadIdx.x;

    // ---- staging: issue ALL loads into regs first (pinned live), then write LDS ----
    vfloat4 stg0, stg1, stg2, stg3;
    {
        int k0i = tid, k1i = tid + 256, k2i = tid + 512, k3i = tid + 768;
        auto addr = [&](int k) {
            int ch   = k / CH_CHUNKS;
            int rem  = k - ch * CH_CHUNKS;
            int rem2 = min(rem, 125);
            int r    = rem2 / CHROW;
            int c4   = rem2 - r * CHROW;
            int gr   = min(v0 + r, H - 1);
            int gc   = min(u0 + c4 * 4, W - 4);
            return fmap + (size_t)(cb + ch) * HW + (size_t)gr * W + gc;
        };
        stg0 = *(const vfloat4*)addr(k0i);
        stg1 = *(const vfloat4*)addr(k1i);
        stg2 = *(const vfloat4*)addr(k2i);
        stg3 = (k3i < BLK_CHUNKS) ? *(const vfloat4*)addr(k3i) : vfloat4{0,0,0,0};
        // Force all four to be simultaneously live -> 16 data VGPRs, 4 loads in flight.
        asm volatile("" : "+v"(stg0), "+v"(stg1), "+v"(stg2), "+v"(stg3));
        *(vfloat4*)&lds[k0i * 4] = stg0;
        *(vfloat4*)&lds[k1i * 4] = stg1;
        *(vfloat4*)&lds[k2i * 4] = stg2;
        if (k3i < BLK_CHUNKS) *(vfloat4*)&lds[k3i * 4] = stg3;
    }
    __syncthreads();

    float dsf = (float)dsp[0];

    // ---- gather from LDS: 2 lanes per point, float2 reads ----
    int s = starts[bin], e = starts[bin + 1];
    int q = tid & 1;                 // channel quad within the 8
    const float* chbase = &lds[q * 4 * CH_F];
    float* midbase = mid + ((size_t)(cg >> 1) * N) * 16 + (cg & 1) * 8 + q * 4;
    for (int p = s + (tid >> 1); p < e; p += 128) {
        float2 pq = sortedUV[p];     // 8B; 2 lanes share the load line
        float u = pq.x / dsf, v = pq.y / dsf;
        int ul = (int)u, vl = (int)v;
        float du = u - (float)ul, dv = v - (float)vl;

        float w00 = (1.0f - dv) * (1.0f - du);
        float w10 = dv * (1.0f - du);
        float w01 = (1.0f - dv) * du;
        float w11 = dv * du;

        const float* base = chbase + (vl - v0) * RWF + (ul - u0);
        float r[4];
#pragma unroll
        for (int c = 0; c < 4; ++c) {
            vfloat2 lo = *(const vfloat2*)(base + c * CH_F);        // f00,f01
            vfloat2 hi = *(const vfloat2*)(base + c * CH_F + RWF);  // f10,f11
            r[c] = lo.x * w00 + hi.x * w10 + lo.y * w01 + hi.y * w11;
        }
        vfloat4 rv = {r[0], r[1], r[2], r[3]};
        *(vfloat4*)(midbase + (size_t)p * 16) = rv;  // 32B/2 lanes: full sector
    }
}

// k5: both-sides-coalesced permutation. 64 dest points per block; per point 8
// chunks of 64B (paired-cg layout), 4 lanes/point cover one 64B chunk per round.
__global__ __launch_bounds__(256) void k5_permute(const float* __restrict__ mid,
                                                  const int* __restrict__ inv,
                                                  float* __restrict__ out, int N) {
    __shared__ float tile[64 * 132];    // 33,792 B
    __shared__ int   sp[64];
    int n0 = blockIdx.x * 64;
    int t  = threadIdx.x;
    int cnt = min(64, N - n0);

    if (t < 64) sp[t] = (t < cnt) ? inv[n0 + t] : 0;
    __syncthreads();

    int j  = t >> 2;                // point 0..63
    int q4 = t & 3;                 // 16B quarter of the 64B chunk
    vfloat4 g[8];
#pragma unroll
    for (int r = 0; r < 8; ++r) {   // r = cg pair (g2)
        if (j < cnt)
            g[r] = *(const vfloat4*)(mid + ((size_t)r * N + sp[j]) * 16 + q4 * 4);
    }
#pragma unroll
    for (int r = 0; r < 8; ++r) {
        if (j < cnt)
            *(vfloat4*)&tile[j * 132 + r * 16 + q4 * 4] = g[r];  // channels r*16+q4*4..+4
    }
    __syncthreads();

    int jj = t & 63;
    for (int s = 0; s < 32; ++s) {
        int c = s * 4 + (t >> 6);
        if (jj < cnt)
            __builtin_nontemporal_store(tile[jj * 132 + c], out + (size_t)c * N + n0 + jj);
    }
}

// ---- Fallback (R2 structure, known-good) if ws too small ----
constexpr int F_CPG = 2;
constexpr int F_CG  = C / F_CPG;
constexpr int F_GPX = F_CG / 8;

__global__ __launch_bounds__(256) void fallback_kernel(
    const float* __restrict__ fmap, const float* __restrict__ uv,
    const int* __restrict__ dsp, float* __restrict__ out, int N, int NBX)
{
    int bid = blockIdx.x;
    int xcd = bid & 7;
    int jj  = bid >> 3;
    int g_local = jj / NBX;
    int nb      = jj - g_local * NBX;
    int g   = xcd * F_GPX + g_local;

    int n = nb * 256 + threadIdx.x;
    if (n >= N) return;

    float dsf = (float)dsp[0];
    float2 p = ((const float2*)uv)[n];
    float u = p.x / dsf, v = p.y / dsf;
    int u_lo = (int)u, v_lo = (int)v;
    float du = u - (float)u_lo, dv = v - (float)v_lo;

    float w00 = (1.0f - dv) * (1.0f - du);
    float w10 = dv * (1.0f - du);
    float w01 = (1.0f - dv) * du;
    float w11 = dv * du;

    int cbase = g * F_CPG;
    const float* fp = fmap + (size_t)cbase * HW + (size_t)v_lo * W + u_lo;
    float*       op = out  + (size_t)cbase * N + n;
#pragma unroll
    for (int c = 0; c < F_CPG; ++c) {
        float f00 = fp[0], f01 = fp[1], f10 = fp[W], f11 = fp[W + 1];
        float r = f00 * w00 + f10 * w10 + f01 * w01 + f11 * w11;
        __builtin_nontemporal_store(r, op);
        fp += HW; op += N;
    }
}

extern "C" void kernel_launch(void* const* d_in, const int* in_sizes, int n_in,
                              void* d_out, int out_size, void* d_ws, size_t ws_size,
                              hipStream_t stream)
{
    const float* fmap = (const float*)d_in[0];
    const float* uv   = (const float*)d_in[1];
    const int*   dsp  = (const int*)d_in[2];
    float*       out  = (float*)d_out;

    int N = in_sizes[1] / 2;

    // ws layout
    size_t off_hist   = 0;
    size_t off_cursor = 8192;      // NBINS=1197 ints = 4788 B
    size_t off_starts = 16384;     // NBINS+1 ints
    size_t off_inv    = 24576;
    size_t off_suv    = off_inv + (((size_t)N * 4 + 255) & ~(size_t)255);
    size_t off_mid    = off_suv + (((size_t)N * 8 + 255) & ~(size_t)255);
    size_t need       = off_mid + (size_t)N * C * 4;

    if (ws_size < need) {
        int NBX = (N + 255) / 256;
        dim3 grid(NBX * F_CG);
        fallback_kernel<<<grid, dim3(256), 0, stream>>>(fmap, uv, dsp, out, N, NBX);
        return;
    }

    char* ws = (char*)d_ws;
    int*    hist     = (int*)(ws + off_hist);
    int*    cursor   = (int*)(ws + off_cursor);
    int*    starts   = (int*)(ws + off_starts);
    int*    inv      = (int*)(ws + off_inv);
    float2* sortedUV = (float2*)(ws + off_suv);
    float*  mid      = (float*)(ws + off_mid);

    int nb = (N + 255) / 256;
    k0_zero<<<1, 512, 0, stream>>>(hist, cursor);
    k1_count<<<nb, 256, 0, stream>>>(uv, dsp, hist, N);
    k2_scan<<<1, 1024, 0, stream>>>(hist, starts, cursor);
    k3_scatter<<<nb, 256, 0, stream>>>(uv, dsp, cursor, sortedUV, inv, N);
    k4_resample<<<NBINS * NCG, 256, 0, stream>>>(fmap, sortedUV, starts, dsp, mid, N);
    k5_permute<<<(N + 63) / 64, 256, 0, stream>>>(mid, inv, out, N);
}

// Round 15
// 226.098 us; speedup vs baseline: 1.0269x; 1.0269x over previous
//
#include <hip/hip_runtime.h>

// Bilinear resampling: feature_map [C,H,W] fp32, target_uv [N,2] fp32, downscale (int scalar)
// out [C,N] fp32.
//
// R15: measured-best composition. R12 aux (k0_zero + 1024t scan) + k4 with
// sched_barrier-batched register staging (R13, 143us) + 1-LANE-PER-POINT gather
// (halves weight-math/records/store-instrs) + paired-cg mid + R12 k5.
constexpr int C = 128, H = 376, W = 1248;
constexpr int HW = H * W;

constexpr int BIN  = 20;
constexpr int BU   = (W + BIN - 1) / BIN;   // 63
constexpr int BV   = (H + BIN - 1) / BIN;   // 19
constexpr int NBINS = BU * BV;              // 1197
constexpr int CPG  = 8;                     // channels per k4 block
constexpr int NCG  = C / CPG;               // 16
constexpr int ROWS = BIN + 1;               // 21 region rows
constexpr int CHROW = 6;                    // float4 chunks per row (24 floats >= 21)
constexpr int RWF  = CHROW * 4;             // 24 floats row stride
constexpr int CH_CHUNKS = ROWS * CHROW + 1; // 127 chunks (126 used + 1 pad)
constexpr int CH_F = CH_CHUNKS * 4;         // 508 floats
constexpr int BLK_CHUNKS = CPG * CH_CHUNKS; // 1016 chunks -> 16,256 B LDS
constexpr int STG = (BLK_CHUNKS + 255) / 256; // 4 staging registers (float4)

typedef float vfloat4 __attribute__((ext_vector_type(4)));

__global__ __launch_bounds__(512) void k0_zero(int* hist, int* cursor) {
    for (int i = threadIdx.x; i < NBINS; i += 512) { hist[i] = 0; cursor[i] = 0; }
}

__global__ __launch_bounds__(256) void k1_count(const float* __restrict__ uv,
                                                const int* __restrict__ dsp,
                                                int* __restrict__ hist, int N) {
    __shared__ int lh[NBINS];
    for (int i = threadIdx.x; i < NBINS; i += 256) lh[i] = 0;
    __syncthreads();
    int n = blockIdx.x * 256 + threadIdx.x;
    if (n < N) {
        float dsf = (float)dsp[0];
        float2 p = ((const float2*)uv)[n];
        int ul = (int)(p.x / dsf);
        int vl = (int)(p.y / dsf);
        atomicAdd(&lh[(vl / BIN) * BU + (ul / BIN)], 1);
    }
    __syncthreads();
    for (int i = threadIdx.x; i < NBINS; i += 256)
        if (lh[i]) atomicAdd(hist + i, lh[i]);
}

// 2-chunk carry scan (NBINS=1197 > 1024) — R12's measured-good version.
__global__ __launch_bounds__(1024) void k2_scan(const int* __restrict__ hist,
                                                int* __restrict__ starts,
                                                int* __restrict__ cursor) {
    __shared__ int sh[1024];
    __shared__ int carry_s;
    int t = threadIdx.x;
    if (t == 0) { carry_s = 0; starts[0] = 0; }
    __syncthreads();
    constexpr int NCHUNK = (NBINS + 1023) / 1024;
    for (int chunk = 0; chunk < NCHUNK; ++chunk) {
        int i = chunk * 1024 + t;
        int val = (i < NBINS) ? hist[i] : 0;
        sh[t] = val;
        __syncthreads();
        for (int off = 1; off < 1024; off <<= 1) {
            int v = (t >= off) ? sh[t - off] : 0;
            __syncthreads();
            sh[t] += v;
            __syncthreads();
        }
        int cbase = carry_s;
        int incl  = sh[t] + cbase;
        if (i < NBINS) {
            starts[i + 1] = incl;
            cursor[i] = incl - val;      // exclusive
        }
        __syncthreads();
        if (t == 1023) carry_s = cbase + sh[1023];
        __syncthreads();
    }
}

__global__ __launch_bounds__(256) void k3_scatter(const float* __restrict__ uv,
                                                  const int* __restrict__ dsp,
                                                  int* __restrict__ cursor,
                                                  float2* __restrict__ sortedUV,
                                                  int* __restrict__ inv, int N) {
    int n = blockIdx.x * 256 + threadIdx.x;
    if (n >= N) return;
    float dsf = (float)dsp[0];
    float2 p = ((const float2*)uv)[n];
    int ul = (int)(p.x / dsf);
    int vl = (int)(p.y / dsf);
    int bin = (vl / BIN) * BU + (ul / BIN);
    int pos = atomicAdd(cursor + bin, 1);
    sortedUV[pos] = p;            // 8B record; k4 re-derives everything
    inv[n] = pos;                 // coalesced: dest-side permutation index
}

// k4: (bin, cg) blocks. sched_barrier-batched register staging of 21x24 x 8ch.
// Gather: 1 LANE PER POINT (all 8 channels), paired-cg mid[cg>>1][p][16],
// this block's half at (cg&1)*8 (2x16B stores, same line).
__global__ __launch_bounds__(256) void k4_resample(const float* __restrict__ fmap,
                                                   const float2* __restrict__ sortedUV,
                                                   const int* __restrict__ starts,
                                                   const int* __restrict__ dsp,
                                                   float* __restrict__ mid, int N) {
    __shared__ float lds[BLK_CHUNKS * 4];   // 16,256 B -> 8 blocks/CU

    int bin = blockIdx.x >> 4;      // / NCG
    int cg  = blockIdx.x & 15;      // % NCG
    int bu  = bin % BU;
    int bv  = bin / BU;
    int u0  = bu * BIN;
    int v0  = bv * BIN;
    int cb  = cg * CPG;
    int tid = threadIdx.x;

    // ---- staging: issue ALL loads into regs first, then write LDS ----
    vfloat4 stg[STG];
#pragma unroll
    for (int i = 0; i < STG; ++i) {
        int k = tid + i * 256;
        if (k < BLK_CHUNKS) {
            int ch   = k / CH_CHUNKS;
            int rem  = k - ch * CH_CHUNKS;
            int rem2 = min(rem, 125);          // pad chunk -> duplicate harmless load
            int r    = rem2 / CHROW;
            int c4   = rem2 - r * CHROW;
            int gr   = min(v0 + r, H - 1);
            int gc   = min(u0 + c4 * 4, W - 4);
            stg[i] = *(const vfloat4*)(fmap + (size_t)(cb + ch) * HW + (size_t)gr * W + gc);
        }
    }
    __builtin_amdgcn_sched_barrier(0);         // R13's measured +13us: batch the loads
#pragma unroll
    for (int i = 0; i < STG; ++i) {
        int k = tid + i * 256;
        if (k < BLK_CHUNKS)
            *(vfloat4*)&lds[k * 4] = stg[i];   // chunk-linear: ch*508 + r*24 + col
    }
    __syncthreads();

    float dsf = (float)dsp[0];

    // ---- gather from LDS: 1 lane per point, 8 channels per lane ----
    int s = starts[bin], e = starts[bin + 1];
    float* midbase = mid + ((size_t)(cg >> 1) * N) * 16 + (cg & 1) * 8;
    for (int p = s + tid; p < e; p += 256) {
        float2 pq = sortedUV[p];     // coalesced 8B
        float u = pq.x / dsf, v = pq.y / dsf;
        int ul = (int)u, vl = (int)v;
        float du = u - (float)ul, dv = v - (float)vl;

        float w00 = (1.0f - dv) * (1.0f - du);
        float w10 = dv * (1.0f - du);
        float w01 = (1.0f - dv) * du;
        float w11 = dv * du;

        const float* base = &lds[(vl - v0) * RWF + (ul - u0)];
        float r[CPG];
#pragma unroll
        for (int c = 0; c < CPG; ++c) {
            float f00 = base[c * CH_F];
            float f01 = base[c * CH_F + 1];
            float f10 = base[c * CH_F + RWF];
            float f11 = base[c * CH_F + RWF + 1];
            r[c] = f00 * w00 + f10 * w10 + f01 * w01 + f11 * w11;
        }
        vfloat4 lo = {r[0], r[1], r[2], r[3]};
        vfloat4 hi = {r[4], r[5], r[6], r[7]};
        float* mp = midbase + (size_t)p * 16;
        *(vfloat4*)mp = lo;                    // 32B to one line (2 stores, same line)
        *(vfloat4*)(mp + 4) = hi;
    }
}

// k5: both-sides-coalesced permutation. 64 dest points per block; per point 8
// chunks of 64B (paired-cg layout), 4 lanes/point cover one 64B chunk per round.
__global__ __launch_bounds__(256) void k5_permute(const float* __restrict__ mid,
                                                  const int* __restrict__ inv,
                                                  float* __restrict__ out, int N) {
    __shared__ float tile[64 * 132];    // 33,792 B
    __shared__ int   sp[64];
    int n0 = blockIdx.x * 64;
    int t  = threadIdx.x;
    int cnt = min(64, N - n0);

    if (t < 64) sp[t] = (t < cnt) ? inv[n0 + t] : 0;
    __syncthreads();

    int j  = t >> 2;                // point 0..63
    int q4 = t & 3;                 // 16B quarter of the 64B chunk
    vfloat4 g[8];
#pragma unroll
    for (int r = 0; r < 8; ++r) {   // r = cg pair (g2)
        if (j < cnt)
            g[r] = *(const vfloat4*)(mid + ((size_t)r * N + sp[j]) * 16 + q4 * 4);
    }
#pragma unroll
    for (int r = 0; r < 8; ++r) {
        if (j < cnt)
            *(vfloat4*)&tile[j * 132 + r * 16 + q4 * 4] = g[r];  // channels r*16+q4*4..+4
    }
    __syncthreads();

    int jj = t & 63;
    for (int s = 0; s < 32; ++s) {
        int c = s * 4 + (t >> 6);
        if (jj < cnt)
            __builtin_nontemporal_store(tile[jj * 132 + c], out + (size_t)c * N + n0 + jj);
    }
}

// ---- Fallback (R2 structure, known-good) if ws too small ----
constexpr int F_CPG = 2;
constexpr int F_CG  = C / F_CPG;
constexpr int F_GPX = F_CG / 8;

__global__ __launch_bounds__(256) void fallback_kernel(
    const float* __restrict__ fmap, const float* __restrict__ uv,
    const int* __restrict__ dsp, float* __restrict__ out, int N, int NBX)
{
    int bid = blockIdx.x;
    int xcd = bid & 7;
    int jj  = bid >> 3;
    int g_local = jj / NBX;
    int nb      = jj - g_local * NBX;
    int g   = xcd * F_GPX + g_local;

    int n = nb * 256 + threadIdx.x;
    if (n >= N) return;

    float dsf = (float)dsp[0];
    float2 p = ((const float2*)uv)[n];
    float u = p.x / dsf, v = p.y / dsf;
    int u_lo = (int)u, v_lo = (int)v;
    float du = u - (float)u_lo, dv = v - (float)v_lo;

    float w00 = (1.0f - dv) * (1.0f - du);
    float w10 = dv * (1.0f - du);
    float w01 = (1.0f - dv) * du;
    float w11 = dv * du;

    int cbase = g * F_CPG;
    const float* fp = fmap + (size_t)cbase * HW + (size_t)v_lo * W + u_lo;
    float*       op = out  + (size_t)cbase * N + n;
#pragma unroll
    for (int c = 0; c < F_CPG; ++c) {
        float f00 = fp[0], f01 = fp[1], f10 = fp[W], f11 = fp[W + 1];
        float r = f00 * w00 + f10 * w10 + f01 * w01 + f11 * w11;
        __builtin_nontemporal_store(r, op);
        fp += HW; op += N;
    }
}

extern "C" void kernel_launch(void* const* d_in, const int* in_sizes, int n_in,
                              void* d_out, int out_size, void* d_ws, size_t ws_size,
                              hipStream_t stream)
{
    const float* fmap = (const float*)d_in[0];
    const float* uv   = (const float*)d_in[1];
    const int*   dsp  = (const int*)d_in[2];
    float*       out  = (float*)d_out;

    int N = in_sizes[1] / 2;

    // ws layout
    size_t off_hist   = 0;
    size_t off_cursor = 8192;      // NBINS=1197 ints = 4788 B
    size_t off_starts = 16384;     // NBINS+1 ints
    size_t off_inv    = 24576;
    size_t off_suv    = off_inv + (((size_t)N * 4 + 255) & ~(size_t)255);
    size_t off_mid    = off_suv + (((size_t)N * 8 + 255) & ~(size_t)255);
    size_t need       = off_mid + (size_t)N * C * 4;

    if (ws_size < need) {
        int NBX = (N + 255) / 256;
        dim3 grid(NBX * F_CG);
        fallback_kernel<<<grid, dim3(256), 0, stream>>>(fmap, uv, dsp, out, N, NBX);
        return;
    }

    char* ws = (char*)d_ws;
    int*    hist     = (int*)(ws + off_hist);
    int*    cursor   = (int*)(ws + off_cursor);
    int*    starts   = (int*)(ws + off_starts);
    int*    inv      = (int*)(ws + off_inv);
    float2* sortedUV = (float2*)(ws + off_suv);
    float*  mid      = (float*)(ws + off_mid);

    int nb = (N + 255) / 256;
    k0_zero<<<1, 512, 0, stream>>>(hist, cursor);
    k1_count<<<nb, 256, 0, stream>>>(uv, dsp, hist, N);
    k2_scan<<<1, 1024, 0, stream>>>(hist, starts, cursor);
    k3_scatter<<<nb, 256, 0, stream>>>(uv, dsp, cursor, sortedUV, inv, N);
    k4_resample<<<NBINS * NCG, 256, 0, stream>>>(fmap, sortedUV, starts, dsp, mid, N);
    k5_permute<<<(N + 63) / 64, 256, 0, stream>>>(mid, inv, out, N);
}

// Round 16
// 221.847 us; speedup vs baseline: 1.0466x; 1.0192x over previous
//
#include <hip/hip_runtime.h>

// Bilinear resampling: feature_map [C,H,W] fp32, target_uv [N,2] fp32, downscale (int scalar)
// out [C,N] fp32.
//
// R16: composition of measured-best halves. k4 = R10's 137us kernel verbatim
// (uint4 records w/ precomputed du,dv; 2 lanes/point; batched reg staging +
// sched_barrier) with paired-cg midbase (R12's k5-fast layout). Aux + k5 = R12.
constexpr int C = 128, H = 376, W = 1248;
constexpr int HW = H * W;

constexpr int BIN  = 20;
constexpr int BU   = (W + BIN - 1) / BIN;   // 63
constexpr int BV   = (H + BIN - 1) / BIN;   // 19
constexpr int NBINS = BU * BV;              // 1197
constexpr int CPG  = 8;                     // channels per k4 block
constexpr int NCG  = C / CPG;               // 16
constexpr int ROWS = BIN + 1;               // 21 region rows
constexpr int CHROW = 6;                    // float4 chunks per row (24 floats >= 21)
constexpr int RWF  = CHROW * 4;             // 24 floats row stride
constexpr int CH_CHUNKS = ROWS * CHROW + 1; // 127 chunks (126 used + 1 pad)
constexpr int CH_F = CH_CHUNKS * 4;         // 508 floats: quad stride 2032 % 32 = 16
constexpr int BLK_CHUNKS = CPG * CH_CHUNKS; // 1016 chunks -> 16,256 B LDS
constexpr int STG = (BLK_CHUNKS + 255) / 256; // 4 staging registers (float4)

typedef float vfloat4 __attribute__((ext_vector_type(4)));

__global__ __launch_bounds__(512) void k0_zero(int* hist, int* cursor) {
    for (int i = threadIdx.x; i < NBINS; i += 512) { hist[i] = 0; cursor[i] = 0; }
}

__global__ __launch_bounds__(256) void k1_count(const float* __restrict__ uv,
                                                const int* __restrict__ dsp,
                                                int* __restrict__ hist, int N) {
    __shared__ int lh[NBINS];
    for (int i = threadIdx.x; i < NBINS; i += 256) lh[i] = 0;
    __syncthreads();
    int n = blockIdx.x * 256 + threadIdx.x;
    if (n < N) {
        float dsf = (float)dsp[0];
        float2 p = ((const float2*)uv)[n];
        int ul = (int)(p.x / dsf);
        int vl = (int)(p.y / dsf);
        atomicAdd(&lh[(vl / BIN) * BU + (ul / BIN)], 1);
    }
    __syncthreads();
    for (int i = threadIdx.x; i < NBINS; i += 256)
        if (lh[i]) atomicAdd(hist + i, lh[i]);
}

// 2-chunk carry scan (NBINS=1197 > 1024)
__global__ __launch_bounds__(1024) void k2_scan(const int* __restrict__ hist,
                                                int* __restrict__ starts,
                                                int* __restrict__ cursor) {
    __shared__ int sh[1024];
    __shared__ int carry_s;
    int t = threadIdx.x;
    if (t == 0) { carry_s = 0; starts[0] = 0; }
    __syncthreads();
    constexpr int NCHUNK = (NBINS + 1023) / 1024;
    for (int chunk = 0; chunk < NCHUNK; ++chunk) {
        int i = chunk * 1024 + t;
        int val = (i < NBINS) ? hist[i] : 0;
        sh[t] = val;
        __syncthreads();
        for (int off = 1; off < 1024; off <<= 1) {
            int v = (t >= off) ? sh[t - off] : 0;
            __syncthreads();
            sh[t] += v;
            __syncthreads();
        }
        int cbase = carry_s;
        int incl  = sh[t] + cbase;
        if (i < NBINS) {
            starts[i + 1] = incl;
            cursor[i] = incl - val;      // exclusive
        }
        __syncthreads();
        if (t == 1023) carry_s = cbase + sh[1023];
        __syncthreads();
    }
}

__global__ __launch_bounds__(256) void k3_scatter(const float* __restrict__ uv,
                                                  const int* __restrict__ dsp,
                                                  int* __restrict__ cursor,
                                                  uint4* __restrict__ sorted,
                                                  int* __restrict__ inv, int N) {
    int n = blockIdx.x * 256 + threadIdx.x;
    if (n >= N) return;
    float dsf = (float)dsp[0];
    float2 p = ((const float2*)uv)[n];
    float u = p.x / dsf, v = p.y / dsf;
    int ul = (int)u, vl = (int)v;
    float du = u - (float)ul, dv = v - (float)vl;
    int bin = (vl / BIN) * BU + (ul / BIN);
    int pos = atomicAdd(cursor + bin, 1);
    uint4 rec;
    rec.x = (unsigned)(ul | (vl << 16));
    rec.y = __float_as_uint(du);
    rec.z = __float_as_uint(dv);
    rec.w = (unsigned)n;
    sorted[pos] = rec;
    inv[n] = pos;                 // coalesced: dest-side permutation index
}

// k4: (bin, cg) blocks. R10's 137us body: batched reg staging of 21x24 x 8ch,
// 2 lanes/point gather from LDS, 16B store per lane -> paired-cg mid:
// mid[cg>>1][p][16] with this block's half at (cg&1)*8.
__global__ __launch_bounds__(256) void k4_resample(const float* __restrict__ fmap,
                                                   const uint4* __restrict__ sorted,
                                                   const int* __restrict__ starts,
                                                   float* __restrict__ mid, int N) {
    __shared__ float lds[BLK_CHUNKS * 4];   // 16,256 B -> 8 blocks/CU

    int bin = blockIdx.x >> 4;      // / NCG
    int cg  = blockIdx.x & 15;      // % NCG
    int bu  = bin % BU;
    int bv  = bin / BU;
    int u0  = bu * BIN;
    int v0  = bv * BIN;
    int cb  = cg * CPG;
    int tid = threadIdx.x;

    // ---- staging: issue ALL loads into regs first, then write LDS ----
    vfloat4 stg[STG];
#pragma unroll
    for (int i = 0; i < STG; ++i) {
        int k = tid + i * 256;
        if (k < BLK_CHUNKS) {
            int ch   = k / CH_CHUNKS;
            int rem  = k - ch * CH_CHUNKS;
            int rem2 = min(rem, 125);          // pad chunk -> duplicate harmless load
            int r    = rem2 / CHROW;
            int c4   = rem2 - r * CHROW;
            int gr   = min(v0 + r, H - 1);
            int gc   = min(u0 + c4 * 4, W - 4);
            stg[i] = *(const vfloat4*)(fmap + (size_t)(cb + ch) * HW + (size_t)gr * W + gc);
        }
    }
    __builtin_amdgcn_sched_barrier(0);         // keep the 4 loads batched in flight
#pragma unroll
    for (int i = 0; i < STG; ++i) {
        int k = tid + i * 256;
        if (k < BLK_CHUNKS)
            *(vfloat4*)&lds[k * 4] = stg[i];   // chunk-linear: ch*508 + r*24 + col
    }
    __syncthreads();

    // ---- gather from LDS: 2 lanes per point (R10 body) ----
    int s = starts[bin], e = starts[bin + 1];
    int q = tid & 1;                 // channel quad within the 8
    const float* chbase = &lds[q * 4 * CH_F];
    float* midbase = mid + ((size_t)(cg >> 1) * N) * 16 + (cg & 1) * 8 + q * 4;
    for (int p = s + (tid >> 1); p < e; p += 128) {
        uint4 pt = sorted[p];        // 16B; 2 lanes share the line
        int ul = (int)(pt.x & 0xffffu);
        int vl = (int)(pt.x >> 16);
        float du = __uint_as_float(pt.y);
        float dv = __uint_as_float(pt.z);

        float w00 = (1.0f - dv) * (1.0f - du);
        float w10 = dv * (1.0f - du);
        float w01 = (1.0f - dv) * du;
        float w11 = dv * du;

        const float* base = chbase + (vl - v0) * RWF + (ul - u0);
        float r[4];
#pragma unroll
        for (int c = 0; c < 4; ++c) {
            float f00 = base[c * CH_F];
            float f01 = base[c * CH_F + 1];
            float f10 = base[c * CH_F + RWF];
            float f11 = base[c * CH_F + RWF + 1];
            r[c] = f00 * w00 + f10 * w10 + f01 * w01 + f11 * w11;
        }
        vfloat4 rv = {r[0], r[1], r[2], r[3]};
        *(vfloat4*)(midbase + (size_t)p * 16) = rv;  // 32B/2 lanes: full sector
    }
}

// k5: both-sides-coalesced permutation (R12). 64 dest points per block; per point
// 8 chunks of 64B (paired-cg layout), 4 lanes/point cover one 64B chunk per round.
__global__ __launch_bounds__(256) void k5_permute(const float* __restrict__ mid,
                                                  const int* __restrict__ inv,
                                                  float* __restrict__ out, int N) {
    __shared__ float tile[64 * 132];    // 33,792 B
    __shared__ int   sp[64];
    int n0 = blockIdx.x * 64;
    int t  = threadIdx.x;
    int cnt = min(64, N - n0);

    if (t < 64) sp[t] = (t < cnt) ? inv[n0 + t] : 0;
    __syncthreads();

    int j  = t >> 2;                // point 0..63
    int q4 = t & 3;                 // 16B quarter of the 64B chunk
    vfloat4 g[8];
#pragma unroll
    for (int r = 0; r < 8; ++r) {   // r = cg pair (g2)
        if (j < cnt)
            g[r] = *(const vfloat4*)(mid + ((size_t)r * N + sp[j]) * 16 + q4 * 4);
    }
#pragma unroll
    for (int r = 0; r < 8; ++r) {
        if (j < cnt)
            *(vfloat4*)&tile[j * 132 + r * 16 + q4 * 4] = g[r];  // channels r*16+q4*4..+4
    }
    __syncthreads();

    int jj = t & 63;
    for (int s = 0; s < 32; ++s) {
        int c = s * 4 + (t >> 6);
        if (jj < cnt)
            __builtin_nontemporal_store(tile[jj * 132 + c], out + (size_t)c * N + n0 + jj);
    }
}

// ---- Fallback (R2 structure, known-good) if ws too small ----
constexpr int F_CPG = 2;
constexpr int F_CG  = C / F_CPG;
constexpr int F_GPX = F_CG / 8;

__global__ __launch_bounds__(256) void fallback_kernel(
    const float* __restrict__ fmap, const float* __restrict__ uv,
    const int* __restrict__ dsp, float* __restrict__ out, int N, int NBX)
{
    int bid = blockIdx.x;
    int xcd = bid & 7;
    int jj  = bid >> 3;
    int g_local = jj / NBX;
    int nb      = jj - g_local * NBX;
    int g   = xcd * F_GPX + g_local;

    int n = nb * 256 + threadIdx.x;
    if (n >= N) return;

    float dsf = (float)dsp[0];
    float2 p = ((const float2*)uv)[n];
    float u = p.x / dsf, v = p.y / dsf;
    int u_lo = (int)u, v_lo = (int)v;
    float du = u - (float)u_lo, dv = v - (float)v_lo;

    float w00 = (1.0f - dv) * (1.0f - du);
    float w10 = dv * (1.0f - du);
    float w01 = (1.0f - dv) * du;
    float w11 = dv * du;

    int cbase = g * F_CPG;
    const float* fp = fmap + (size_t)cbase * HW + (size_t)v_lo * W + u_lo;
    float*       op = out  + (size_t)cbase * N + n;
#pragma unroll
    for (int c = 0; c < F_CPG; ++c) {
        float f00 = fp[0], f01 = fp[1], f10 = fp[W], f11 = fp[W + 1];
        float r = f00 * w00 + f10 * w10 + f01 * w01 + f11 * w11;
        __builtin_nontemporal_store(r, op);
        fp += HW; op += N;
    }
}

extern "C" void kernel_launch(void* const* d_in, const int* in_sizes, int n_in,
                              void* d_out, int out_size, void* d_ws, size_t ws_size,
                              hipStream_t stream)
{
    const float* fmap = (const float*)d_in[0];
    const float* uv   = (const float*)d_in[1];
    const int*   dsp  = (const int*)d_in[2];
    float*       out  = (float*)d_out;

    int N = in_sizes[1] / 2;

    // ws layout
    size_t off_hist   = 0;
    size_t off_cursor = 8192;      // NBINS=1197 ints = 4788 B
    size_t off_starts = 16384;     // NBINS+1 ints
    size_t off_inv    = 24576;
    size_t off_sorted = off_inv + (((size_t)N * 4 + 255) & ~(size_t)255);
    size_t off_mid    = off_sorted + (((size_t)N * 16 + 255) & ~(size_t)255);
    size_t need       = off_mid + (size_t)N * C * 4;

    if (ws_size < need) {
        int NBX = (N + 255) / 256;
        dim3 grid(NBX * F_CG);
        fallback_kernel<<<grid, dim3(256), 0, stream>>>(fmap, uv, dsp, out, N, NBX);
        return;
    }

    char* ws = (char*)d_ws;
    int*   hist   = (int*)(ws + off_hist);
    int*   cursor = (int*)(ws + off_cursor);
    int*   starts = (int*)(ws + off_starts);
    int*   inv    = (int*)(ws + off_inv);
    uint4* sorted = (uint4*)(ws + off_sorted);
    float* mid    = (float*)(ws + off_mid);

    int nb = (N + 255) / 256;
    k0_zero<<<1, 512, 0, stream>>>(hist, cursor);
    k1_count<<<nb, 256, 0, stream>>>(uv, dsp, hist, N);
    k2_scan<<<1, 1024, 0, stream>>>(hist, starts, cursor);
    k3_scatter<<<nb, 256, 0, stream>>>(uv, dsp, cursor, sorted, inv, N);
    k4_resample<<<NBINS * NCG, 256, 0, stream>>>(fmap, sorted, starts, mid, N);
    k5_permute<<<(N + 63) / 64, 256, 0, stream>>>(mid, inv, out, N);
}

// Round 17
// 202.563 us; speedup vs baseline: 1.1462x; 1.0952x over previous
//
#include <hip/hip_runtime.h>

// Bilinear resampling: feature_map [C,H,W] fp32, target_uv [N,2] fp32, downscale (int scalar)
// out [C,N] fp32.
//
// R17: CPG=16 so ONE block writes each point's full 64B mid chunk (contiguous
// streaming stores, R10's winning property) while k5 keeps R12's fast 8x64B
// read geometry. BIN=16 -> 21.8KB LDS (7 blocks/CU); CH_F=340 -> quad stride
// 1360 % 32 = 16 (2-way bank conflict = free), fixing R9's 4-way.
constexpr int C = 128, H = 376, W = 1248;
constexpr int HW = H * W;

constexpr int BIN  = 16;
constexpr int BU   = (W + BIN - 1) / BIN;   // 78
constexpr int BV   = (H + BIN - 1) / BIN;   // 24
constexpr int NBINS = BU * BV;              // 1872
constexpr int CPG  = 16;                    // channels per k4 block
constexpr int NCG  = C / CPG;               // 8
constexpr int ROWS = BIN + 1;               // 17 region rows
constexpr int CHROW = 5;                    // float4 chunks per row (20 floats >= 17)
constexpr int RWF  = CHROW * 4;             // 20 floats row stride
constexpr int CH_CHUNKS = ROWS * CHROW;     // 85 chunks (no pad needed)
constexpr int CH_F = CH_CHUNKS * 4;         // 340 floats; 4*340=1360 % 32 = 16 -> 2-way only
constexpr int BLK_CHUNKS = CPG * CH_CHUNKS; // 1360 chunks -> 21,760 B LDS
constexpr int STG = (BLK_CHUNKS + 255) / 256; // 6 staging registers (float4)

typedef float vfloat4 __attribute__((ext_vector_type(4)));

__global__ __launch_bounds__(512) void k0_zero(int* hist, int* cursor) {
    for (int i = threadIdx.x; i < NBINS; i += 512) { hist[i] = 0; cursor[i] = 0; }
}

__global__ __launch_bounds__(256) void k1_count(const float* __restrict__ uv,
                                                const int* __restrict__ dsp,
                                                int* __restrict__ hist, int N) {
    __shared__ int lh[NBINS];
    for (int i = threadIdx.x; i < NBINS; i += 256) lh[i] = 0;
    __syncthreads();
    int n = blockIdx.x * 256 + threadIdx.x;
    if (n < N) {
        float dsf = (float)dsp[0];
        float2 p = ((const float2*)uv)[n];
        int ul = (int)(p.x / dsf);
        int vl = (int)(p.y / dsf);
        atomicAdd(&lh[(vl / BIN) * BU + (ul / BIN)], 1);
    }
    __syncthreads();
    for (int i = threadIdx.x; i < NBINS; i += 256)
        if (lh[i]) atomicAdd(hist + i, lh[i]);
}

// 2-chunk carry scan (NBINS=1872 > 1024)
__global__ __launch_bounds__(1024) void k2_scan(const int* __restrict__ hist,
                                                int* __restrict__ starts,
                                                int* __restrict__ cursor) {
    __shared__ int sh[1024];
    __shared__ int carry_s;
    int t = threadIdx.x;
    if (t == 0) { carry_s = 0; starts[0] = 0; }
    __syncthreads();
    constexpr int NCHUNK = (NBINS + 1023) / 1024;
    for (int chunk = 0; chunk < NCHUNK; ++chunk) {
        int i = chunk * 1024 + t;
        int val = (i < NBINS) ? hist[i] : 0;
        sh[t] = val;
        __syncthreads();
        for (int off = 1; off < 1024; off <<= 1) {
            int v = (t >= off) ? sh[t - off] : 0;
            __syncthreads();
            sh[t] += v;
            __syncthreads();
        }
        int cbase = carry_s;
        int incl  = sh[t] + cbase;
        if (i < NBINS) {
            starts[i + 1] = incl;
            cursor[i] = incl - val;      // exclusive
        }
        __syncthreads();
        if (t == 1023) carry_s = cbase + sh[1023];
        __syncthreads();
    }
}

__global__ __launch_bounds__(256) void k3_scatter(const float* __restrict__ uv,
                                                  const int* __restrict__ dsp,
                                                  int* __restrict__ cursor,
                                                  uint4* __restrict__ sorted,
                                                  int* __restrict__ inv, int N) {
    int n = blockIdx.x * 256 + threadIdx.x;
    if (n >= N) return;
    float dsf = (float)dsp[0];
    float2 p = ((const float2*)uv)[n];
    float u = p.x / dsf, v = p.y / dsf;
    int ul = (int)u, vl = (int)v;
    float du = u - (float)ul, dv = v - (float)vl;
    int bin = (vl / BIN) * BU + (ul / BIN);
    int pos = atomicAdd(cursor + bin, 1);
    uint4 rec;
    rec.x = (unsigned)(ul | (vl << 16));
    rec.y = __float_as_uint(du);
    rec.z = __float_as_uint(dv);
    rec.w = (unsigned)n;
    sorted[pos] = rec;
    inv[n] = pos;                 // coalesced: dest-side permutation index
}

// k4: (bin, cg) blocks. Batched reg staging of 17x20(pad) x 16ch.
// Gather: 4 lanes/point (quad q -> channels q*4..q*4+3); stores form a
// CONTIGUOUS 64B per point in cg-major mid[cg][p][16] -> pure streaming.
__global__ __launch_bounds__(256) void k4_resample(const float* __restrict__ fmap,
                                                   const uint4* __restrict__ sorted,
                                                   const int* __restrict__ starts,
                                                   float* __restrict__ mid, int N) {
    __shared__ float lds[BLK_CHUNKS * 4];   // 21,760 B -> 7 blocks/CU

    int bin = blockIdx.x >> 3;      // / NCG
    int cg  = blockIdx.x & 7;       // % NCG
    int bu  = bin % BU;
    int bv  = bin / BU;
    int u0  = bu * BIN;
    int v0  = bv * BIN;
    int cb  = cg * CPG;
    int tid = threadIdx.x;

    // ---- staging: issue ALL loads into regs first, then write LDS ----
    vfloat4 stg[STG];
#pragma unroll
    for (int i = 0; i < STG; ++i) {
        int k = tid + i * 256;
        if (k < BLK_CHUNKS) {
            int ch   = k / CH_CHUNKS;
            int rem  = k - ch * CH_CHUNKS;
            int r    = rem / CHROW;
            int c4   = rem - r * CHROW;
            int gr   = min(v0 + r, H - 1);
            int gc   = min(u0 + c4 * 4, W - 4);
            stg[i] = *(const vfloat4*)(fmap + (size_t)(cb + ch) * HW + (size_t)gr * W + gc);
        }
    }
    __builtin_amdgcn_sched_barrier(0);         // keep the loads batched in flight
#pragma unroll
    for (int i = 0; i < STG; ++i) {
        int k = tid + i * 256;
        if (k < BLK_CHUNKS)
            *(vfloat4*)&lds[k * 4] = stg[i];   // chunk-linear: ch*340 + r*20 + col
    }
    __syncthreads();

    // ---- gather from LDS: 4 lanes per point ----
    int s = starts[bin], e = starts[bin + 1];
    int q = tid & 3;                 // channel quad within the 16
    const float* chbase = &lds[q * 4 * CH_F];
    float* midbase = mid + ((size_t)cg * N) * 16 + q * 4;
    for (int p = s + (tid >> 2); p < e; p += 64) {
        uint4 pt = sorted[p];        // 16B; 4 lanes share the line
        int ul = (int)(pt.x & 0xffffu);
        int vl = (int)(pt.x >> 16);
        float du = __uint_as_float(pt.y);
        float dv = __uint_as_float(pt.z);

        float w00 = (1.0f - dv) * (1.0f - du);
        float w10 = dv * (1.0f - du);
        float w01 = (1.0f - dv) * du;
        float w11 = dv * du;

        const float* base = chbase + (vl - v0) * RWF + (ul - u0);
        float r[4];
#pragma unroll
        for (int c = 0; c < 4; ++c) {
            float f00 = base[c * CH_F];
            float f01 = base[c * CH_F + 1];
            float f10 = base[c * CH_F + RWF];
            float f11 = base[c * CH_F + RWF + 1];
            r[c] = f00 * w00 + f10 * w10 + f01 * w01 + f11 * w11;
        }
        vfloat4 rv = {r[0], r[1], r[2], r[3]};
        // 4 lanes write q*16B -> one contiguous 64B line per point, contiguous in p
        *(vfloat4*)(midbase + (size_t)p * 16) = rv;
    }
}

// k5: both-sides-coalesced permutation (R12 geometry). 64 dest points per block;
// per point 8 chunks of 64B (cg-major CPG=16 layout), 4 lanes/point per chunk.
__global__ __launch_bounds__(256) void k5_permute(const float* __restrict__ mid,
                                                  const int* __restrict__ inv,
                                                  float* __restrict__ out, int N) {
    __shared__ float tile[64 * 132];    // 33,792 B
    __shared__ int   sp[64];
    int n0 = blockIdx.x * 64;
    int t  = threadIdx.x;
    int cnt = min(64, N - n0);

    if (t < 64) sp[t] = (t < cnt) ? inv[n0 + t] : 0;
    __syncthreads();

    int j  = t >> 2;                // point 0..63
    int q4 = t & 3;                 // 16B quarter of the 64B chunk
    vfloat4 g[8];
#pragma unroll
    for (int r = 0; r < 8; ++r) {   // r = cg (16 channels each)
        if (j < cnt)
            g[r] = *(const vfloat4*)(mid + ((size_t)r * N + sp[j]) * 16 + q4 * 4);
    }
#pragma unroll
    for (int r = 0; r < 8; ++r) {
        if (j < cnt)
            *(vfloat4*)&tile[j * 132 + r * 16 + q4 * 4] = g[r];  // channels r*16+q4*4..+4
    }
    __syncthreads();

    int jj = t & 63;
    for (int s = 0; s < 32; ++s) {
        int c = s * 4 + (t >> 6);
        if (jj < cnt)
            __builtin_nontemporal_store(tile[jj * 132 + c], out + (size_t)c * N + n0 + jj);
    }
}

// ---- Fallback (R2 structure, known-good) if ws too small ----
constexpr int F_CPG = 2;
constexpr int F_CG  = C / F_CPG;
constexpr int F_GPX = F_CG / 8;

__global__ __launch_bounds__(256) void fallback_kernel(
    const float* __restrict__ fmap, const float* __restrict__ uv,
    const int* __restrict__ dsp, float* __restrict__ out, int N, int NBX)
{
    int bid = blockIdx.x;
    int xcd = bid & 7;
    int jj  = bid >> 3;
    int g_local = jj / NBX;
    int nb      = jj - g_local * NBX;
    int g   = xcd * F_GPX + g_local;

    int n = nb * 256 + threadIdx.x;
    if (n >= N) return;

    float dsf = (float)dsp[0];
    float2 p = ((const float2*)uv)[n];
    float u = p.x / dsf, v = p.y / dsf;
    int u_lo = (int)u, v_lo = (int)v;
    float du = u - (float)u_lo, dv = v - (float)v_lo;

    float w00 = (1.0f - dv) * (1.0f - du);
    float w10 = dv * (1.0f - du);
    float w01 = (1.0f - dv) * du;
    float w11 = dv * du;

    int cbase = g * F_CPG;
    const float* fp = fmap + (size_t)cbase * HW + (size_t)v_lo * W + u_lo;
    float*       op = out  + (size_t)cbase * N + n;
#pragma unroll
    for (int c = 0; c < F_CPG; ++c) {
        float f00 = fp[0], f01 = fp[1], f10 = fp[W], f11 = fp[W + 1];
        float r = f00 * w00 + f10 * w10 + f01 * w01 + f11 * w11;
        __builtin_nontemporal_store(r, op);
        fp += HW; op += N;
    }
}

extern "C" void kernel_launch(void* const* d_in, const int* in_sizes, int n_in,
                              void* d_out, int out_size, void* d_ws, size_t ws_size,
                              hipStream_t stream)
{
    const float* fmap = (const float*)d_in[0];
    const float* uv   = (const float*)d_in[1];
    const int*   dsp  = (const int*)d_in[2];
    float*       out  = (float*)d_out;

    int N = in_sizes[1] / 2;

    // ws layout
    size_t off_hist   = 0;
    size_t off_cursor = 8192;      // NBINS=1872 ints = 7488 B
    size_t off_starts = 16384;     // NBINS+1 ints = 7492 B
    size_t off_inv    = 24576;
    size_t off_sorted = off_inv + (((size_t)N * 4 + 255) & ~(size_t)255);
    size_t off_mid    = off_sorted + (((size_t)N * 16 + 255) & ~(size_t)255);
    size_t need       = off_mid + (size_t)N * C * 4;

    if (ws_size < need) {
        int NBX = (N + 255) / 256;
        dim3 grid(NBX * F_CG);
        fallback_kernel<<<grid, dim3(256), 0, stream>>>(fmap, uv, dsp, out, N, NBX);
        return;
    }

    char* ws = (char*)d_ws;
    int*   hist   = (int*)(ws + off_hist);
    int*   cursor = (int*)(ws + off_cursor);
    int*   starts = (int*)(ws + off_starts);
    int*   inv    = (int*)(ws + off_inv);
    uint4* sorted = (uint4*)(ws + off_sorted);
    float* mid    = (float*)(ws + off_mid);

    int nb = (N + 255) / 256;
    k0_zero<<<1, 512, 0, stream>>>(hist, cursor);
    k1_count<<<nb, 256, 0, stream>>>(uv, dsp, hist, N);
    k2_scan<<<1, 1024, 0, stream>>>(hist, starts, cursor);
    k3_scatter<<<nb, 256, 0, stream>>>(uv, dsp, cursor, sorted, inv, N);
    k4_resample<<<NBINS * NCG, 256, 0, stream>>>(fmap, sorted, starts, mid, N);
    k5_permute<<<(N + 63) / 64, 256, 0, stream>>>(mid, inv, out, N);
}